// Round 3
// baseline (199.078 us; speedup 1.0000x reference)
//
#include <hip/hip_runtime.h>
#include <hip/hip_bf16.h>
#include <stdint.h>

typedef __bf16 bf16;
typedef __attribute__((ext_vector_type(8))) __bf16 bf16x8;
typedef __attribute__((ext_vector_type(4))) __bf16 bf16x4;
typedef __attribute__((ext_vector_type(4))) float f32x4;

// ---------------- workspace layout (bytes) ----------------
// xb  [32768,512] bf16  @0          (dead after gemm_qkv -> attn bf16)
// Wb  [1536,512]  bf16  @33554432
// qb  [32768,512] bf16  @35127296
// kT  [4,512,8192] bf16 @68681728   (written directly by gemm_qkv epilogue)
// vT  [4,512,8192] bf16 @102236160
// KVb [4,512,512] bf16  @135790592
// split-K partials P live in d_out (64 MB, dead until ln_kernel).
#define OFF_XB   0L
#define OFF_WB   33554432L
#define OFF_QB   35127296L
#define OFF_KT   68681728L
#define OFF_VT   102236160L
#define OFF_KVB  135790592L
#define WS_NEED  137887744L

// ---------------- async global->LDS (16B per lane) ----------------
typedef const __attribute__((address_space(1))) void* gas_p;
typedef __attribute__((address_space(3))) void* las_p;

__device__ __forceinline__ void gload16(const void* g, void* l) {
  __builtin_amdgcn_global_load_lds((gas_p)(uintptr_t)g,
                                   (las_p)(uint32_t)(uintptr_t)l, 16, 0, 0);
}

// ================= 256x128 pipelined GEMM core (BK=64, 8 waves) =================
// C[256,128] += A[256, k0:k0+nt*64] * B[128, k0:k0+nt*64]^T ; K contiguous both.
// 512 threads = 8 waves (4M x 2N); wave tile 64x64 = 4x4 16x16x32 fragments.
// LDS: 3 rotating buffers of (A 32KB + B 16KB); prefetch depth 2 tiles;
// counted s_waitcnt vmcnt(6) (one tile in flight) + raw s_barrier per K-tile.
// Swizzle: byte ^= ((byte>>7)&7)<<4  (involution, 16B-granular) applied to
// ds_read addresses AND pre-applied to global_load_lds SOURCE addresses.
#define TILE_B 49152
#define A_B    32768

__device__ __forceinline__ uint32_t swz(uint32_t b) {
  return b ^ (((b >> 7) & 7u) << 4);
}

__device__ __forceinline__ void gemm_core8(
    const bf16* __restrict__ Ab, const bf16* __restrict__ Bb,
    long lda, long ldb, int nt, char* smem, f32x4 (&acc)[4][4])
{
  const int tid = threadIdx.x, lane = tid & 63, wid = tid >> 6;
  const int wr = wid >> 1, wc = wid & 1;

  // staging: 6 chunks/thread/tile (A:4, B:2); global src pre-swizzled
  long goffA[4], goffB[2];
  uint32_t ldsA[4], ldsB[2];
#pragma unroll
  for (int i = 0; i < 4; ++i) {
    uint32_t b = (uint32_t)((i * 512 + wid * 64 + lane) * 16);
    uint32_t l = swz(b);
    goffA[i] = (long)(l >> 7) * (lda * 2) + (l & 127);
    ldsA[i] = i * 8192 + wid * 1024;               // wave-uniform dest base
  }
#pragma unroll
  for (int i = 0; i < 2; ++i) {
    uint32_t b = (uint32_t)((i * 512 + wid * 64 + lane) * 16);
    uint32_t l = swz(b);
    goffB[i] = (long)(l >> 7) * (ldb * 2) + (l & 127);
    ldsB[i] = A_B + i * 8192 + wid * 1024;
  }
  // fragment read offsets (k-tile-invariant, swizzled)
  uint32_t offA[4][2], offB[4][2];
#pragma unroll
  for (int m = 0; m < 4; ++m)
#pragma unroll
    for (int ks = 0; ks < 2; ++ks) {
      offA[m][ks] = swz((uint32_t)((wr * 64 + m * 16 + (lane & 15)) * 128 +
                                   ks * 64 + (lane >> 4) * 16));
      offB[m][ks] = A_B + swz((uint32_t)((wc * 64 + m * 16 + (lane & 15)) * 128 +
                                         ks * 64 + (lane >> 4) * 16));
    }

  const char* Ag = (const char*)Ab;
  const char* Bg = (const char*)Bb;

#define STAGE(t, buf) do {                                   \
    long kb = (long)(t) * 128;                               \
    char* sb_ = smem + (buf) * TILE_B;                       \
    gload16(Ag + goffA[0] + kb, sb_ + ldsA[0]);              \
    gload16(Ag + goffA[1] + kb, sb_ + ldsA[1]);              \
    gload16(Ag + goffA[2] + kb, sb_ + ldsA[2]);              \
    gload16(Ag + goffA[3] + kb, sb_ + ldsA[3]);              \
    gload16(Bg + goffB[0] + kb, sb_ + ldsB[0]);              \
    gload16(Bg + goffB[1] + kb, sb_ + ldsB[1]);              \
  } while (0)

  // prologue: stage tiles 0,1; wait tile 0; publish
  STAGE(0, 0);
  if (nt > 1) STAGE(1, 1);
  if (nt > 1) asm volatile("s_waitcnt vmcnt(6)" ::: "memory");
  else        asm volatile("s_waitcnt vmcnt(0)" ::: "memory");
  __builtin_amdgcn_s_barrier();
  asm volatile("" ::: "memory");

  int cur = 0, b2 = 2;
  for (int t = 0; t < nt; ++t) {
    if (t + 2 < nt) STAGE(t + 2, b2);   // buf b2 == tile t-1's buffer: dead
    const char* base = smem + cur * TILE_B;
    bf16x8 af[4][2], bw[4][2];
#pragma unroll
    for (int m = 0; m < 4; ++m) {
      af[m][0] = *(const bf16x8*)(base + offA[m][0]);
      af[m][1] = *(const bf16x8*)(base + offA[m][1]);
    }
#pragma unroll
    for (int n = 0; n < 4; ++n) {
      bw[n][0] = *(const bf16x8*)(base + offB[n][0]);
      bw[n][1] = *(const bf16x8*)(base + offB[n][1]);
    }
    __builtin_amdgcn_s_setprio(1);
#pragma unroll
    for (int m = 0; m < 4; ++m)
#pragma unroll
      for (int n = 0; n < 4; ++n) {
        acc[m][n] = __builtin_amdgcn_mfma_f32_16x16x32_bf16(af[m][0], bw[n][0], acc[m][n], 0, 0, 0);
        acc[m][n] = __builtin_amdgcn_mfma_f32_16x16x32_bf16(af[m][1], bw[n][1], acc[m][n], 0, 0, 0);
      }
    __builtin_amdgcn_s_setprio(0);
    if (t + 1 < nt) {
      if (t + 2 < nt) asm volatile("s_waitcnt vmcnt(6)" ::: "memory");  // tile t+1 landed
      else            asm volatile("s_waitcnt vmcnt(0)" ::: "memory");
      __builtin_amdgcn_s_barrier();
      asm volatile("" ::: "memory");
    }
    cur = (cur == 2) ? 0 : cur + 1;
    b2  = (b2 == 2) ? 0 : b2 + 1;
  }
  // make LDS safe to reuse for epilogue
  asm volatile("s_waitcnt vmcnt(0)" ::: "memory");
  __builtin_amdgcn_s_barrier();
  asm volatile("" ::: "memory");
#undef STAGE
}

// ---------------- casts ----------------
__global__ void cast_x_kernel(const float* __restrict__ in, bf16* __restrict__ out, int n8) {
  int i = blockIdx.x * blockDim.x + threadIdx.x;
  int stride = gridDim.x * blockDim.x;
  for (; i < n8; i += stride) {
    const float* p = in + (long)i * 8;
    float4 a = *(const float4*)p;
    float4 b = *(const float4*)(p + 4);
    bf16x8 o;
    o[0] = (bf16)a.x; o[1] = (bf16)a.y; o[2] = (bf16)a.z; o[3] = (bf16)a.w;
    o[4] = (bf16)b.x; o[5] = (bf16)b.y; o[6] = (bf16)b.z; o[7] = (bf16)b.w;
    *(bf16x8*)(out + (long)i * 8) = o;
  }
}

__global__ void cast_w_kernel(const float* __restrict__ Wq, const float* __restrict__ Wk,
                              const float* __restrict__ Wv, bf16* __restrict__ Wb) {
  int i = blockIdx.x * 256 + threadIdx.x;            // 98304 chunks of 8
  const float* src = (i < 32768) ? Wq : (i < 65536) ? Wk : Wv;
  long j = (long)(i & 32767) * 8;
  float4 a = *(const float4*)(src + j);
  float4 b = *(const float4*)(src + j + 4);
  bf16x8 o;
  o[0] = (bf16)a.x; o[1] = (bf16)a.y; o[2] = (bf16)a.z; o[3] = (bf16)a.w;
  o[4] = (bf16)b.x; o[5] = (bf16)b.y; o[6] = (bf16)b.z; o[7] = (bf16)b.w;
  *(bf16x8*)(Wb + (long)i * 8) = o;
}

// ---------------- fused QKV projection GEMM ----------------
// grid (128, 12): bm = 256-row tile of x; tn = 128-col tile of [q|k|v].
__global__ __launch_bounds__(512, 1) void gemm_qkv(
    const bf16* __restrict__ A, const bf16* __restrict__ Bw,
    const float* __restrict__ bq, const float* __restrict__ bk, const float* __restrict__ bv,
    bf16* __restrict__ qout, bf16* __restrict__ kTout, bf16* __restrict__ vTout)
{
  __shared__ __align__(16) char smem[TILE_B * 3];
  const int bm = blockIdx.x, tn = blockIdx.y;
  const bf16* Ab = A + (long)bm * 256 * 512;
  const bf16* Bb = Bw + (long)tn * 128 * 512;

  f32x4 acc[4][4] = {};
  gemm_core8(Ab, Bb, 512, 512, 8, smem, acc);

  const int tid = threadIdx.x, lane = tid & 63, wid = tid >> 6;
  const int wr = wid >> 1, wc = wid & 1;
  const int seg = tn >> 2;                            // 0=q 1=k 2=v (block-uniform)
  const float* bias = (seg == 0) ? bq : (seg == 1) ? bk : bv;
  const int colbase0 = (tn & 3) * 128;

  if (seg == 0) {
    bf16* Ct = (bf16*)smem;                           // [256][136]
#pragma unroll
    for (int n = 0; n < 4; ++n) {
      int colL = wc * 64 + n * 16 + (lane & 15);
      float bia = bias[colbase0 + colL];
#pragma unroll
      for (int m = 0; m < 4; ++m) {
        int r0 = wr * 64 + m * 16 + (lane >> 4) * 4;
#pragma unroll
        for (int j = 0; j < 4; ++j) {
          float v = acc[m][n][j] + bia;
          v = (v > 0.f) ? (v + 1.f) : __expf(v);      // elu1
          Ct[(r0 + j) * 136 + colL] = (bf16)v;
        }
      }
    }
    __builtin_amdgcn_s_barrier();
    asm volatile("" ::: "memory");
    const long rowbase = (long)bm * 256;
    const int r_ = tid >> 4, c8 = (tid & 15) * 8;
#pragma unroll
    for (int p = 0; p < 8; ++p) {
      int row = p * 32 + r_;
      *(bf16x8*)(qout + (rowbase + row) * 512 + colbase0 + c8) =
          *(const bf16x8*)(Ct + row * 136 + c8);
    }
  } else {
    bf16* Ct = (bf16*)smem;                           // transposed [128][264]
    bf16* outT = (seg == 1) ? kTout : vTout;
#pragma unroll
    for (int n = 0; n < 4; ++n) {
      int colL = wc * 64 + n * 16 + (lane & 15);      // d_local
      float bia = bias[colbase0 + colL];
#pragma unroll
      for (int m = 0; m < 4; ++m) {
        int r0 = wr * 64 + m * 16 + (lane >> 4) * 4;  // s_local
        bf16x4 pk;
#pragma unroll
        for (int j = 0; j < 4; ++j) {
          float v = acc[m][n][j] + bia;
          if (seg == 1) v = (v > 0.f) ? (v + 1.f) : __expf(v);
          pk[j] = (bf16)v;
        }
        *(bf16x4*)(Ct + colL * 264 + r0) = pk;
      }
    }
    __builtin_amdgcn_s_barrier();
    asm volatile("" ::: "memory");
    const int b = bm >> 5;                            // 32 x 256-row tiles per batch
    const long sb = (long)(bm & 31) * 256;
    const int d_ = tid >> 5, s8 = (tid & 31) * 8;
    bf16* outB = outT + (long)b * 512 * 8192 + sb;
#pragma unroll
    for (int p = 0; p < 8; ++p) {
      int d = p * 16 + d_;
      *(bf16x8*)(outB + (long)(colbase0 + d) * 8192 + s8) =
          *(const bf16x8*)(Ct + d * 264 + s8);
    }
  }
}

// ---------------- KV^T GEMM, split-K=8 (partials in d_out) ----------------
// C[e,d] = sum_s v[s,e]*k[s,d] ; A = vT rows e (BM=256), B = kT rows d (BN=128).
__global__ __launch_bounds__(512, 1) void gemm_kv(
    const bf16* __restrict__ vT, const bf16* __restrict__ kT, float* __restrict__ P)
{
  __shared__ __align__(16) char smem[TILE_B * 3];
  const int sp = blockIdx.x, sk = blockIdx.y, bz = blockIdx.z;
  const int te = sp >> 2, td = sp & 3;
  const bf16* Ab = vT + (long)bz * 512 * 8192 + (long)te * 256 * 8192 + sk * 1024;
  const bf16* Bb = kT + (long)bz * 512 * 8192 + (long)td * 128 * 8192 + sk * 1024;

  f32x4 acc[4][4] = {};
  gemm_core8(Ab, Bb, 8192, 8192, 16, smem, acc);

  const int lane = threadIdx.x & 63, wid = threadIdx.x >> 6;
  const int wr = wid >> 1, wc = wid & 1;
  float* Cb = P + ((long)sk * 4 + bz) * 262144;
#pragma unroll
  for (int n = 0; n < 4; ++n) {
    int d = td * 128 + wc * 64 + n * 16 + (lane & 15);
#pragma unroll
    for (int m = 0; m < 4; ++m) {
      int e0 = te * 256 + wr * 64 + m * 16 + (lane >> 4) * 4;
#pragma unroll
      for (int j = 0; j < 4; ++j)
        Cb[(long)(e0 + j) * 512 + d] = acc[m][n][j];   // 64B-contiguous segments
    }
  }
}

__global__ void reduce_kv(const float* __restrict__ P, bf16* __restrict__ KVb) {
  long o = ((long)blockIdx.x * 256 + threadIdx.x) * 4;   // over 4*512*512 elems
  int b = (int)(o >> 18);
  long rem = o & 262143L;
  float4 s = make_float4(0.f, 0.f, 0.f, 0.f);
  for (int sk = 0; sk < 8; ++sk) {
    float4 p = *(const float4*)(P + ((long)sk * 4 + b) * 262144 + rem);
    s.x += p.x; s.y += p.y; s.z += p.z; s.w += p.w;
  }
  bf16x4 ov;
  ov[0] = (bf16)s.x; ov[1] = (bf16)s.y; ov[2] = (bf16)s.z; ov[3] = (bf16)s.w;
  *(bf16x4*)(KVb + o) = ov;
}

// ---------------- attn GEMM: C[s,e] = sum_d q[s,d]*KVT[e,d] ----------------
__global__ __launch_bounds__(512, 1) void gemm_attn(
    const bf16* __restrict__ Q, const bf16* __restrict__ KVb, bf16* __restrict__ attn)
{
  __shared__ __align__(16) char smem[TILE_B * 3];
  const int bm = blockIdx.x, tn = blockIdx.y;
  const int b = bm >> 5;                              // 32 x 256-row tiles per batch
  const bf16* Ab = Q + (long)bm * 256 * 512;
  const bf16* Bb = KVb + (long)b * 262144 + (long)tn * 128 * 512;

  f32x4 acc[4][4] = {};
  gemm_core8(Ab, Bb, 512, 512, 8, smem, acc);

  const int tid = threadIdx.x, lane = tid & 63, wid = tid >> 6;
  const int wr = wid >> 1, wc = wid & 1;
  bf16* Ct = (bf16*)smem;                             // [256][136]
#pragma unroll
  for (int n = 0; n < 4; ++n) {
    int colL = wc * 64 + n * 16 + (lane & 15);
#pragma unroll
    for (int m = 0; m < 4; ++m) {
      int r0 = wr * 64 + m * 16 + (lane >> 4) * 4;
#pragma unroll
      for (int j = 0; j < 4; ++j)
        Ct[(r0 + j) * 136 + colL] = (bf16)acc[m][n][j];
    }
  }
  __builtin_amdgcn_s_barrier();
  asm volatile("" ::: "memory");
  const long rowbase = (long)bm * 256;
  const int colbase0 = tn * 128;
  const int r_ = tid >> 4, c8 = (tid & 15) * 8;
#pragma unroll
  for (int p = 0; p < 8; ++p) {
    int row = p * 32 + r_;
    *(bf16x8*)(attn + (rowbase + row) * 512 + colbase0 + c8) =
        *(const bf16x8*)(Ct + row * 136 + c8);
  }
}

// ---------------- residual add + LayerNorm (one wave per row of 512) ----------------
__global__ __launch_bounds__(256) void ln_kernel(
    const float* __restrict__ x, const bf16* __restrict__ attn,
    const float* __restrict__ gamma, const float* __restrict__ beta,
    float* __restrict__ out)
{
  const int row = blockIdx.x * 4 + (threadIdx.x >> 6);
  const int lane = threadIdx.x & 63;
  const float* xr = x + (long)row * 512;
  const ushort* ar = (const ushort*)attn + (long)row * 512;

  float4 xa = *(const float4*)&xr[lane * 8];
  float4 xb2 = *(const float4*)&xr[lane * 8 + 4];
  uint4 av = *(const uint4*)&ar[lane * 8];
  const ushort* ap = (const ushort*)&av;

  float y[8];
  y[0] = xa.x; y[1] = xa.y; y[2] = xa.z; y[3] = xa.w;
  y[4] = xb2.x; y[5] = xb2.y; y[6] = xb2.z; y[7] = xb2.w;
  float s1 = 0.f, s2 = 0.f;
#pragma unroll
  for (int j = 0; j < 8; ++j) {
    float aj = __uint_as_float(((unsigned)ap[j]) << 16);
    y[j] += aj;
    s1 += y[j];
    s2 += y[j] * y[j];
  }
#pragma unroll
  for (int off = 32; off > 0; off >>= 1) {
    s1 += __shfl_xor(s1, off);
    s2 += __shfl_xor(s2, off);
  }
  float mu = s1 * (1.f / 512.f);
  float var = s2 * (1.f / 512.f) - mu * mu;
  float rs = rsqrtf(var + 1e-5f);

  float4 g0 = *(const float4*)&gamma[lane * 8];
  float4 g1 = *(const float4*)&gamma[lane * 8 + 4];
  float4 b0 = *(const float4*)&beta[lane * 8];
  float4 b1 = *(const float4*)&beta[lane * 8 + 4];
  float4 o0, o1;
  o0.x = (y[0] - mu) * rs * g0.x + b0.x;
  o0.y = (y[1] - mu) * rs * g0.y + b0.y;
  o0.z = (y[2] - mu) * rs * g0.z + b0.z;
  o0.w = (y[3] - mu) * rs * g0.w + b0.w;
  o1.x = (y[4] - mu) * rs * g1.x + b1.x;
  o1.y = (y[5] - mu) * rs * g1.y + b1.y;
  o1.z = (y[6] - mu) * rs * g1.z + b1.z;
  o1.w = (y[7] - mu) * rs * g1.w + b1.w;
  float* orow = out + (long)row * 512 + lane * 8;
  *(float4*)orow = o0;
  *(float4*)(orow + 4) = o1;
}

// ---------------- launch ----------------
extern "C" void kernel_launch(void* const* d_in, const int* in_sizes, int n_in,
                              void* d_out, int out_size, void* d_ws, size_t ws_size,
                              hipStream_t stream) {
  const float* x     = (const float*)d_in[0];
  const float* Wq    = (const float*)d_in[1];
  const float* bq    = (const float*)d_in[2];
  const float* Wk    = (const float*)d_in[3];
  const float* bk    = (const float*)d_in[4];
  const float* Wv    = (const float*)d_in[5];
  const float* bv    = (const float*)d_in[6];
  const float* gamma = (const float*)d_in[7];
  const float* beta  = (const float*)d_in[8];
  float* out = (float*)d_out;

  if (ws_size < (size_t)WS_NEED) return;   // need ~132 MB scratch

  char* ws = (char*)d_ws;
  bf16* xb   = (bf16*)(ws + OFF_XB);
  bf16* Wb   = (bf16*)(ws + OFF_WB);
  bf16* qb   = (bf16*)(ws + OFF_QB);
  bf16* kT   = (bf16*)(ws + OFF_KT);
  bf16* vT   = (bf16*)(ws + OFF_VT);
  bf16* attn = (bf16*)(ws + OFF_XB);   // xb dead after gemm_qkv
  bf16* KVb  = (bf16*)(ws + OFF_KVB);
  float* P   = (float*)d_out;          // 32 MB of split-K partials; d_out dead until ln

  cast_x_kernel<<<2048, 256, 0, stream>>>(x, xb, 2097152);
  cast_w_kernel<<<384, 256, 0, stream>>>(Wq, Wk, Wv, Wb);
  gemm_qkv<<<dim3(128, 12), 512, 0, stream>>>(xb, Wb, bq, bk, bv, qb, kT, vT);
  gemm_kv<<<dim3(8, 8, 4), 512, 0, stream>>>(vT, kT, P);
  reduce_kv<<<1024, 256, 0, stream>>>(P, KVb);
  gemm_attn<<<dim3(128, 4), 512, 0, stream>>>(qb, KVb, attn);
  ln_kernel<<<8192, 256, 0, stream>>>(x, attn, gamma, beta, out);
}

// Round 4
// 188.199 us; speedup vs baseline: 1.0578x; 1.0578x over previous
//
#include <hip/hip_runtime.h>
#include <hip/hip_bf16.h>
#include <stdint.h>

typedef __bf16 bf16;
typedef __attribute__((ext_vector_type(8))) __bf16 bf16x8;
typedef __attribute__((ext_vector_type(4))) __bf16 bf16x4;
typedef __attribute__((ext_vector_type(4))) float f32x4;

// ---------------- workspace layout (bytes) ----------------
// xb  [32768,512] bf16  @0          (dead after gemm_qkv -> attn bf16)
// Wb  [1536,512]  bf16  @33554432
// qb  [32768,512] bf16  @35127296
// kT  [4,512,8192] bf16 @68681728
// vT  [4,512,8192] bf16 @102236160
// KVb [4,512,512] bf16  @135790592
// split-K partials P [16][4][512][512] f32 live in d_out (67.1 MB, exact fit).
#define OFF_XB   0L
#define OFF_WB   33554432L
#define OFF_QB   35127296L
#define OFF_KT   68681728L
#define OFF_VT   102236160L
#define OFF_KVB  135790592L
#define WS_NEED  137887744L

// ---------------- async global->LDS (16B per lane) ----------------
typedef const __attribute__((address_space(1))) void* gas_p;
typedef __attribute__((address_space(3))) void* las_p;

__device__ __forceinline__ void gload16(const void* g, void* l) {
  __builtin_amdgcn_global_load_lds((gas_p)(uintptr_t)g,
                                   (las_p)(uint32_t)(uintptr_t)l, 16, 0, 0);
}

// swizzle: bits 4-6 ^= bits 7-9 (involution, 16B-granular, within 128B row)
__device__ __forceinline__ uint32_t swz(uint32_t b) {
  return b ^ (((b >> 7) & 7u) << 4);
}

// ================= 256x256 8-phase GEMM core (BK=64, 8 waves) =================
// C[256,256] += A[256,K] * B[256,K]^T ; K contiguous in both (B^T-form).
// 512 threads = 8 waves (wr=wid>>2 in {0,1} M-half-of-wave-tile, wc=wid&3 col quarter).
// Wave output 128x64: m-frags 0-3 in A-half0 rows wr*64+[0,64), 4-7 in half1.
// LDS 128KB: A[d][h] at (d*2+h)*16KB, B[d][h] at 64KB + (d*2+h)*16KB.
// Half-tile = 128 rows x 64k x bf16 = 16KB; staged by 2 gload16/thread.
// 8 phases per 2 K-tiles; stage targets die >=1 phase before issue; vmcnt(4)
// at P4 (tile t1 landed) and P8 (tile t2 landed). Never vmcnt(0) mid-loop.
__device__ __forceinline__ void gemm_core256(
    const char* __restrict__ Ag, const char* __restrict__ Bg,
    long lda_b, long ldb_b, int nt, char* smem, f32x4 (&acc)[8][4])
{
  const int tid = threadIdx.x, lane = tid & 63, wid = tid >> 6;
  const int wr = wid >> 2, wc = wid & 3;

  // staging source offsets (pre-swizzled global), j=0: LDS [0,8K), j=1: [8K,16K)
  const uint32_t l0 = (uint32_t)(tid * 16);
  const uint32_t b0 = swz(l0);
  const uint32_t b1 = swz(l0 + 8192) & 16383u;
  const long srcA0 = (long)(b0 >> 7) * lda_b + (b0 & 127);
  const long srcA1 = (long)(b1 >> 7) * lda_b + (b1 & 127);
  const long srcB0 = (long)(b0 >> 7) * ldb_b + (b0 & 127);
  const long srcB1 = (long)(b1 >> 7) * ldb_b + (b1 & 127);
  const long hA = 128 * lda_b, hB = 128 * ldb_b;

  // reader lane offsets (const parts of addr have no bits<11 -> add == or)
  const uint32_t lp = (uint32_t)((lane & 15) * 128 + ((lane >> 4) * 16));
  const uint32_t lx = (uint32_t)((lane & 7) << 4);
  const uint32_t lo0 = lp ^ lx, lo1 = (lp + 64) ^ lx;
  const char* Abase = smem + wr * 8192;
  const char* Bbase = smem + 65536 + (wc >> 1) * 16384 + (wc & 1) * 8192;

  bf16x8 af[4], bw[2][4];

#define STAGE_A(tau, d, h) do {                                        \
    char* dst_ = smem + ((d) * 2 + (h)) * 16384 + wid * 1024;          \
    const char* s_ = Ag + (long)(h) * hA + (long)(tau) * 128;          \
    gload16(s_ + srcA0, dst_);                                         \
    gload16(s_ + srcA1, dst_ + 8192);                                  \
  } while (0)
#define STAGE_B(tau, d, h) do {                                        \
    char* dst_ = smem + 65536 + ((d) * 2 + (h)) * 16384 + wid * 1024;  \
    const char* s_ = Bg + (long)(h) * hB + (long)(tau) * 128;          \
    gload16(s_ + srcB0, dst_);                                         \
    gload16(s_ + srcB1, dst_ + 8192);                                  \
  } while (0)
#define VMW(cond) do {                                                 \
    if (cond) asm volatile("s_waitcnt vmcnt(4)" ::: "memory");         \
    else      asm volatile("s_waitcnt vmcnt(0)" ::: "memory");         \
  } while (0)
#define PHASE(d, mh, ks, LOADBW, STAGE_STMT, VM_STMT) do {             \
    _Pragma("unroll")                                                  \
    for (int mi = 0; mi < 4; ++mi)                                     \
      af[mi] = *(const bf16x8*)(Abase + (d) * 32768 + (mh) * 16384 +   \
                                mi * 2048 + ((ks) ? lo1 : lo0));       \
    if (LOADBW) {                                                      \
      _Pragma("unroll")                                                \
      for (int n = 0; n < 4; ++n)                                      \
        bw[ks][n] = *(const bf16x8*)(Bbase + (d) * 32768 + n * 2048 +  \
                                     ((ks) ? lo1 : lo0));              \
    }                                                                  \
    STAGE_STMT;                                                        \
    __builtin_amdgcn_s_barrier();                                      \
    asm volatile("s_waitcnt lgkmcnt(0)" ::: "memory");                 \
    __builtin_amdgcn_sched_barrier(0);                                 \
    __builtin_amdgcn_s_setprio(1);                                     \
    _Pragma("unroll")                                                  \
    for (int mi = 0; mi < 4; ++mi)                                     \
      _Pragma("unroll")                                                \
      for (int n = 0; n < 4; ++n)                                      \
        acc[(mh) * 4 + mi][n] = __builtin_amdgcn_mfma_f32_16x16x32_bf16( \
            af[mi], bw[ks][n], acc[(mh) * 4 + mi][n], 0, 0, 0);        \
    __builtin_amdgcn_s_setprio(0);                                     \
    VM_STMT;                                                           \
    __builtin_amdgcn_s_barrier();                                      \
  } while (0)

  // prologue: tile0 all 4 halves + tile1 h0 halves; wait tile0 (4 in flight)
  STAGE_A(0, 0, 0); STAGE_B(0, 0, 0); STAGE_A(0, 0, 1); STAGE_B(0, 0, 1);
  STAGE_A(1, 1, 0); STAGE_B(1, 1, 0);
  asm volatile("s_waitcnt vmcnt(4)" ::: "memory");
  __builtin_amdgcn_s_barrier();

  for (int i = 0; i < (nt >> 1); ++i) {
    const int t1 = 2 * i + 1;
    const bool more = (i + 1 < (nt >> 1));
    PHASE(0, 0, 0, true,  STAGE_B(t1, 1, 1), ((void)0));              // P1
    PHASE(0, 0, 1, true,  STAGE_A(t1, 1, 1), ((void)0));              // P2
    PHASE(0, 1, 0, false, if (more) STAGE_A(t1 + 1, 0, 0), ((void)0));// P3
    PHASE(0, 1, 1, false, if (more) STAGE_B(t1 + 1, 0, 0), VMW(more));// P4
    PHASE(1, 0, 0, true,  if (more) STAGE_A(t1 + 1, 0, 1), ((void)0));// P5
    PHASE(1, 0, 1, true,  if (more) STAGE_B(t1 + 1, 0, 1), ((void)0));// P6
    PHASE(1, 1, 0, false, if (more) STAGE_A(t1 + 2, 1, 0), ((void)0));// P7
    PHASE(1, 1, 1, false, if (more) STAGE_B(t1 + 2, 1, 0), VMW(more));// P8
  }
  // loop exits after vmcnt(0)+barrier on last P8: LDS safe to reuse.
#undef PHASE
#undef VMW
#undef STAGE_B
#undef STAGE_A
}

// ---------------- casts ----------------
__global__ void cast_x_kernel(const float* __restrict__ in, bf16* __restrict__ out, int n8) {
  int i = blockIdx.x * blockDim.x + threadIdx.x;
  int stride = gridDim.x * blockDim.x;
  for (; i < n8; i += stride) {
    const float* p = in + (long)i * 8;
    float4 a = *(const float4*)p;
    float4 b = *(const float4*)(p + 4);
    bf16x8 o;
    o[0] = (bf16)a.x; o[1] = (bf16)a.y; o[2] = (bf16)a.z; o[3] = (bf16)a.w;
    o[4] = (bf16)b.x; o[5] = (bf16)b.y; o[6] = (bf16)b.z; o[7] = (bf16)b.w;
    *(bf16x8*)(out + (long)i * 8) = o;
  }
}

__global__ void cast_w_kernel(const float* __restrict__ Wq, const float* __restrict__ Wk,
                              const float* __restrict__ Wv, bf16* __restrict__ Wb) {
  int i = blockIdx.x * 256 + threadIdx.x;            // 98304 chunks of 8
  const float* src = (i < 32768) ? Wq : (i < 65536) ? Wk : Wv;
  long j = (long)(i & 32767) * 8;
  float4 a = *(const float4*)(src + j);
  float4 b = *(const float4*)(src + j + 4);
  bf16x8 o;
  o[0] = (bf16)a.x; o[1] = (bf16)a.y; o[2] = (bf16)a.z; o[3] = (bf16)a.w;
  o[4] = (bf16)b.x; o[5] = (bf16)b.y; o[6] = (bf16)b.z; o[7] = (bf16)b.w;
  *(bf16x8*)(Wb + (long)i * 8) = o;
}

// ---------------- fused QKV projection GEMM (256x256 tiles) ----------------
// grid (128, 6): bm = 256-row tile; tn = 256-col tile of [q|k|v]; seg = tn>>1.
__global__ __launch_bounds__(512, 1) void gemm_qkv(
    const bf16* __restrict__ A, const bf16* __restrict__ Bw,
    const float* __restrict__ bq, const float* __restrict__ bk, const float* __restrict__ bv,
    bf16* __restrict__ qout, bf16* __restrict__ kTout, bf16* __restrict__ vTout)
{
  __shared__ __align__(16) char smem[131072];
  const int bm = blockIdx.x, tn = blockIdx.y;
  const char* Ag = (const char*)(A + (long)bm * 256 * 512);
  const char* Bg = (const char*)(Bw + (long)tn * 256 * 512);

  f32x4 acc[8][4] = {};
  gemm_core256(Ag, Bg, 1024, 1024, 8, smem, acc);

  const int tid = threadIdx.x, lane = tid & 63, wid = tid >> 6;
  const int wr = wid >> 2, wc = wid & 3;
  const int seg = tn >> 1;                            // 0=q 1=k 2=v
  const float* bias = (seg == 0) ? bq : (seg == 1) ? bk : bv;
  const int colbase0 = (tn & 1) * 256;

  if (seg == 0) {
    bf16* Ct = (bf16*)smem;                           // [128][264] per pass
#pragma unroll 2
    for (int mh = 0; mh < 2; ++mh) {
#pragma unroll
      for (int n = 0; n < 4; ++n) {
        int col = wc * 64 + n * 16 + (lane & 15);
        float bia = bias[colbase0 + col];
#pragma unroll
        for (int mi = 0; mi < 4; ++mi) {
          int r0 = wr * 64 + mi * 16 + (lane >> 4) * 4;
#pragma unroll
          for (int j = 0; j < 4; ++j) {
            float v = acc[mh * 4 + mi][n][j] + bia;
            v = (v > 0.f) ? (v + 1.f) : __expf(v);    // elu1
            Ct[(r0 + j) * 264 + col] = (bf16)v;
          }
        }
      }
      __builtin_amdgcn_s_barrier();
      const long rowbase = (long)bm * 256 + mh * 128;
      const int r_ = tid >> 5, c8 = (tid & 31) * 8;
#pragma unroll
      for (int p = 0; p < 8; ++p) {
        int row = p * 16 + r_;
        *(bf16x8*)(qout + (rowbase + row) * 512 + colbase0 + c8) =
            *(const bf16x8*)(Ct + row * 264 + c8);
      }
      __builtin_amdgcn_s_barrier();
    }
  } else {
    bf16* Ct = (bf16*)smem;                           // transposed [256][136] per pass
    bf16* outT = (seg == 1) ? kTout : vTout;
    const int b = bm >> 5;
    const long sb = (long)(bm & 31) * 256;
    bf16* outB = outT + (long)b * 512 * 8192 + sb;
#pragma unroll 2
    for (int mh = 0; mh < 2; ++mh) {
#pragma unroll
      for (int n = 0; n < 4; ++n) {
        int dl = wc * 64 + n * 16 + (lane & 15);
        float bia = bias[colbase0 + dl];
#pragma unroll
        for (int mi = 0; mi < 4; ++mi) {
          int s0 = wr * 64 + mi * 16 + (lane >> 4) * 4;
          bf16x4 pk;
#pragma unroll
          for (int j = 0; j < 4; ++j) {
            float v = acc[mh * 4 + mi][n][j] + bia;
            if (seg == 1) v = (v > 0.f) ? (v + 1.f) : __expf(v);
            pk[j] = (bf16)v;
          }
          *(bf16x4*)(Ct + dl * 136 + s0) = pk;
        }
      }
      __builtin_amdgcn_s_barrier();
      const int d_ = tid >> 4, s8 = (tid & 15) * 8;
#pragma unroll
      for (int p = 0; p < 8; ++p) {
        int d = p * 32 + d_;
        *(bf16x8*)(outB + (long)(colbase0 + d) * 8192 + mh * 128 + s8) =
            *(const bf16x8*)(Ct + d * 136 + s8);
      }
      __builtin_amdgcn_s_barrier();
    }
  }
}

// ---------------- KV^T GEMM, split-K=16 (partials in d_out) ----------------
// C[e,d] = sum_s v[s,e]*k[s,d]; A = vT rows e (256), B = kT rows d (256).
// grid (16, 16): x = b*4 + te*2 + td, y = sk. K-chunk 512 = 8 tiles.
__global__ __launch_bounds__(512, 1) void gemm_kv(
    const bf16* __restrict__ vT, const bf16* __restrict__ kT, float* __restrict__ P)
{
  __shared__ __align__(16) char smem[131072];
  const int bz = blockIdx.x >> 2, te = (blockIdx.x >> 1) & 1, td = blockIdx.x & 1;
  const int sk = blockIdx.y;
  const char* Ag = (const char*)(vT + (long)bz * 512 * 8192 + (long)te * 256 * 8192 + sk * 512);
  const char* Bg = (const char*)(kT + (long)bz * 512 * 8192 + (long)td * 256 * 8192 + sk * 512);

  f32x4 acc[8][4] = {};
  gemm_core256(Ag, Bg, 16384, 16384, 8, smem, acc);

  const int lane = threadIdx.x & 63, wid = threadIdx.x >> 6;
  const int wr = wid >> 2, wc = wid & 3;
  float* Cb = P + ((long)sk * 4 + bz) * 262144;
#pragma unroll
  for (int mh = 0; mh < 2; ++mh)
#pragma unroll
    for (int n = 0; n < 4; ++n) {
      int d = td * 256 + wc * 64 + n * 16 + (lane & 15);
#pragma unroll
      for (int mi = 0; mi < 4; ++mi) {
        int e0 = te * 256 + mh * 128 + wr * 64 + mi * 16 + (lane >> 4) * 4;
#pragma unroll
        for (int j = 0; j < 4; ++j)
          Cb[(long)(e0 + j) * 512 + d] = acc[mh * 4 + mi][n][j];
      }
    }
}

__global__ void reduce_kv(const float* __restrict__ P, bf16* __restrict__ KVb) {
  long o = ((long)blockIdx.x * 256 + threadIdx.x) * 4;   // over 4*512*512 elems
  int b = (int)(o >> 18);
  long rem = o & 262143L;
  float4 s = make_float4(0.f, 0.f, 0.f, 0.f);
#pragma unroll
  for (int sk = 0; sk < 16; ++sk) {
    float4 p = *(const float4*)(P + ((long)sk * 4 + b) * 262144 + rem);
    s.x += p.x; s.y += p.y; s.z += p.z; s.w += p.w;
  }
  bf16x4 ov;
  ov[0] = (bf16)s.x; ov[1] = (bf16)s.y; ov[2] = (bf16)s.z; ov[3] = (bf16)s.w;
  *(bf16x4*)(KVb + o) = ov;
}

// ---------------- attn GEMM: C[s,e] = sum_d q[s,d]*KVT[e,d] ----------------
// grid (128, 2): bm = 256-row tile of q; tn = 256-col tile of e.
__global__ __launch_bounds__(512, 1) void gemm_attn(
    const bf16* __restrict__ Q, const bf16* __restrict__ KVb, bf16* __restrict__ attn)
{
  __shared__ __align__(16) char smem[131072];
  const int bm = blockIdx.x, tn = blockIdx.y;
  const int b = bm >> 5;
  const char* Ag = (const char*)(Q + (long)bm * 256 * 512);
  const char* Bg = (const char*)(KVb + (long)b * 262144 + (long)tn * 256 * 512);

  f32x4 acc[8][4] = {};
  gemm_core256(Ag, Bg, 1024, 1024, 8, smem, acc);

  const int tid = threadIdx.x, lane = tid & 63, wid = tid >> 6;
  const int wr = wid >> 2, wc = wid & 3;
  bf16* Ct = (bf16*)smem;                             // [128][264] per pass
  const int colbase0 = tn * 256;
#pragma unroll 2
  for (int mh = 0; mh < 2; ++mh) {
#pragma unroll
    for (int n = 0; n < 4; ++n) {
      int col = wc * 64 + n * 16 + (lane & 15);
#pragma unroll
      for (int mi = 0; mi < 4; ++mi) {
        int r0 = wr * 64 + mi * 16 + (lane >> 4) * 4;
#pragma unroll
        for (int j = 0; j < 4; ++j)
          Ct[(r0 + j) * 264 + col] = (bf16)acc[mh * 4 + mi][n][j];
      }
    }
    __builtin_amdgcn_s_barrier();
    const long rowbase = (long)bm * 256 + mh * 128;
    const int r_ = tid >> 5, c8 = (tid & 31) * 8;
#pragma unroll
    for (int p = 0; p < 8; ++p) {
      int row = p * 16 + r_;
      *(bf16x8*)(attn + (rowbase + row) * 512 + colbase0 + c8) =
          *(const bf16x8*)(Ct + row * 264 + c8);
    }
    __builtin_amdgcn_s_barrier();
  }
}

// ---------------- residual add + LayerNorm (one wave per row of 512) ----------------
__global__ __launch_bounds__(256) void ln_kernel(
    const float* __restrict__ x, const bf16* __restrict__ attn,
    const float* __restrict__ gamma, const float* __restrict__ beta,
    float* __restrict__ out)
{
  const int row = blockIdx.x * 4 + (threadIdx.x >> 6);
  const int lane = threadIdx.x & 63;
  const float* xr = x + (long)row * 512;
  const ushort* ar = (const ushort*)attn + (long)row * 512;

  float4 xa = *(const float4*)&xr[lane * 8];
  float4 xb2 = *(const float4*)&xr[lane * 8 + 4];
  uint4 av = *(const uint4*)&ar[lane * 8];
  const ushort* ap = (const ushort*)&av;

  float y[8];
  y[0] = xa.x; y[1] = xa.y; y[2] = xa.z; y[3] = xa.w;
  y[4] = xb2.x; y[5] = xb2.y; y[6] = xb2.z; y[7] = xb2.w;
  float s1 = 0.f, s2 = 0.f;
#pragma unroll
  for (int j = 0; j < 8; ++j) {
    float aj = __uint_as_float(((unsigned)ap[j]) << 16);
    y[j] += aj;
    s1 += y[j];
    s2 += y[j] * y[j];
  }
#pragma unroll
  for (int off = 32; off > 0; off >>= 1) {
    s1 += __shfl_xor(s1, off);
    s2 += __shfl_xor(s2, off);
  }
  float mu = s1 * (1.f / 512.f);
  float var = s2 * (1.f / 512.f) - mu * mu;
  float rs = rsqrtf(var + 1e-5f);

  float4 g0 = *(const float4*)&gamma[lane * 8];
  float4 g1 = *(const float4*)&gamma[lane * 8 + 4];
  float4 b0 = *(const float4*)&beta[lane * 8];
  float4 b1 = *(const float4*)&beta[lane * 8 + 4];
  float4 o0, o1;
  o0.x = (y[0] - mu) * rs * g0.x + b0.x;
  o0.y = (y[1] - mu) * rs * g0.y + b0.y;
  o0.z = (y[2] - mu) * rs * g0.z + b0.z;
  o0.w = (y[3] - mu) * rs * g0.w + b0.w;
  o1.x = (y[4] - mu) * rs * g1.x + b1.x;
  o1.y = (y[5] - mu) * rs * g1.y + b1.y;
  o1.z = (y[6] - mu) * rs * g1.z + b1.z;
  o1.w = (y[7] - mu) * rs * g1.w + b1.w;
  float* orow = out + (long)row * 512 + lane * 8;
  *(float4*)orow = o0;
  *(float4*)(orow + 4) = o1;
}

// ---------------- launch ----------------
extern "C" void kernel_launch(void* const* d_in, const int* in_sizes, int n_in,
                              void* d_out, int out_size, void* d_ws, size_t ws_size,
                              hipStream_t stream) {
  const float* x     = (const float*)d_in[0];
  const float* Wq    = (const float*)d_in[1];
  const float* bq    = (const float*)d_in[2];
  const float* Wk    = (const float*)d_in[3];
  const float* bk    = (const float*)d_in[4];
  const float* Wv    = (const float*)d_in[5];
  const float* bv    = (const float*)d_in[6];
  const float* gamma = (const float*)d_in[7];
  const float* beta  = (const float*)d_in[8];
  float* out = (float*)d_out;

  if (ws_size < (size_t)WS_NEED) return;   // need ~132 MB scratch

  char* ws = (char*)d_ws;
  bf16* xb   = (bf16*)(ws + OFF_XB);
  bf16* Wb   = (bf16*)(ws + OFF_WB);
  bf16* qb   = (bf16*)(ws + OFF_QB);
  bf16* kT   = (bf16*)(ws + OFF_KT);
  bf16* vT   = (bf16*)(ws + OFF_VT);
  bf16* attn = (bf16*)(ws + OFF_XB);   // xb dead after gemm_qkv
  bf16* KVb  = (bf16*)(ws + OFF_KVB);
  float* P   = (float*)d_out;          // 67.1 MB split-K partials; dead until ln

  cast_x_kernel<<<2048, 256, 0, stream>>>(x, xb, 2097152);
  cast_w_kernel<<<384, 256, 0, stream>>>(Wq, Wk, Wv, Wb);
  gemm_qkv<<<dim3(128, 6), 512, 0, stream>>>(xb, Wb, bq, bk, bv, qb, kT, vT);
  gemm_kv<<<dim3(16, 16), 512, 0, stream>>>(vT, kT, P);
  reduce_kv<<<1024, 256, 0, stream>>>(P, KVb);
  gemm_attn<<<dim3(128, 2), 512, 0, stream>>>(qb, KVb, attn);
  ln_kernel<<<8192, 256, 0, stream>>>(x, attn, gamma, beta, out);
}